// Round 2
// baseline (1696.124 us; speedup 1.0000x reference)
//
#include <hip/hip_runtime.h>

// ---------------------------------------------------------------------------
// CriticNetwork: GRU over T=256 steps (B=1024, H=256, F=65) + 2-critic MLP.
// Kernel 1 (gru_kernel): persistent, 256 blocks x 512 thr (8 waves, 2/SIMD).
//   Wh held as bf16 MFMA B-fragments in REGISTERS. Input projection fused
//   (every 4 steps, M = 4 batch x 4 time).
//   THIS ROUND: xp fully register-resident. xp MFMA M-row mapping changed to
//   row i <-> (batch=i>>2, time=i&3) so lane (l15,kg) reg r holds
//   xp(batch=kg, time=t0+r) -> gate reads acc2[j][tt] directly (no LDS, no
//   shuffles, no bf16 round-trip). h kept in a register per lane (ho re-read
//   gone; LDS write remains for other waves' A-fragments). bi/w64/bhn in
//   registers. Particles + weights prefetched (reg double-buffer) across
//   groups. LDS per step: 8x ds_read_b128 (2-way max) + 2 u16 writes.
// Kernel 2 (head_kernel): twin critic MLPs, 32 blocks, MFMA. (unchanged)
// ---------------------------------------------------------------------------

#define TSEQ 256
#define DPDIM 64

typedef float f32x4 __attribute__((ext_vector_type(4)));
typedef __bf16 bf16x8 __attribute__((ext_vector_type(8)));
typedef unsigned short ushort8 __attribute__((ext_vector_type(8)));

static __device__ __forceinline__ unsigned short f2bf(float f) {
  unsigned u = __builtin_bit_cast(unsigned, f);
  return (unsigned short)((u + 0x7fffu + ((u >> 16) & 1u)) >> 16);  // RNE
}
static __device__ __forceinline__ float bf2f(unsigned short h) {
  return __builtin_bit_cast(float, ((unsigned)h) << 16);
}
static __device__ __forceinline__ float sigm(float x) {
  return __builtin_amdgcn_rcpf(1.f + __expf(-x));
}
static __device__ __forceinline__ float tanh_fast(float p) {
  float q = __expf(-2.f * fabsf(p));
  float t = (1.f - q) * __builtin_amdgcn_rcpf(1.f + q);
  return __builtin_bit_cast(float, __builtin_bit_cast(unsigned, t) |
                                   (__builtin_bit_cast(unsigned, p) & 0x80000000u));
}

// ---- GRU kernel LDS layout (bytes) ----
#define OFF_WIT 0         // Wi transposed bf16 [768 n][72 k-stride] = 768*144
#define OFF_H0  110592    // h buf0 bf16 [4 real rows + 1 zero row][272] stride 544B
#define OFF_H1  113312    // h buf1 (same shape)
#define LDS_GRU 116032

#define HSTRIDE 544       // h row stride in bytes (2-way max bank pattern)

__global__ __launch_bounds__(512, 2) void gru_kernel(
    const float* __restrict__ particles, const float* __restrict__ weights,
    const float* __restrict__ Wi, const float* __restrict__ bi,
    const float* __restrict__ Wh, const float* __restrict__ bhn,
    unsigned short* __restrict__ hT)
{
  extern __shared__ char smem[];
  const int tid  = threadIdx.x;
  const int lane = tid & 63;
  const int w    = tid >> 6;      // wave id 0..7
  const int l15  = lane & 15;
  const int kg   = lane >> 4;     // k-group 0..3
  const int b0   = blockIdx.x * 4;

  // ---------------- prologue ----------------
  // Wi rows 0..63 -> LDS transposed bf16 (B-operand friendly: k contiguous per n)
  for (int idx = tid; idx < 64 * 768; idx += 512) {
    int k = idx / 768, n = idx - k * 768;
    *(unsigned short*)(smem + OFF_WIT + n * 144 + k * 2) = f2bf(Wi[idx]);
  }
  // zero both h buffers (incl. the shared zero row 4, never written again)
  for (int idx = tid; idx < (2 * 5 * HSTRIDE) / 4; idx += 512)
    ((unsigned*)(smem + OFF_H0))[idx] = 0u;

  // per-lane bias / weight-channel registers (cols this lane owns)
  const int hcol0 = w * 16 + l15;       // p=0 col; p=1 col = hcol0+128
  float bi_r[6], w64_r[6];
  #pragma unroll
  for (int j = 0; j < 6; ++j) {
    const int col = hcol0 + 128 * j;
    bi_r[j]  = bi[col];
    w64_r[j] = Wi[64 * 768 + col];
  }
  const float bhn0 = bhn[hcol0];
  const float bhn1 = bhn[hcol0 + 128];

  // Wh -> register B-fragments. Wave w owns N-tiles {w+8j}, j=0..5:
  //   j=0,1 -> r-gate tiles (hidden tiles w, w+8); j=2,3 -> z; j=4,5 -> n.
  bf16x8 whb[6][8];
  #pragma unroll
  for (int j = 0; j < 6; ++j) {
    const int tile = w + 8 * j;
    const float* wp = Wh + (size_t)(kg * 8) * 768 + tile * 16 + l15;
    #pragma unroll
    for (int ks = 0; ks < 8; ++ks) {
      ushort8 tmp;
      #pragma unroll
      for (int e = 0; e < 8; ++e)
        tmp[e] = f2bf(wp[(size_t)(ks * 32 + e) * 768]);
      whb[j][ks] = __builtin_bit_cast(bf16x8, tmp);
    }
  }
  __syncthreads();

  // A-fragment source for the recurrence: M-row l15 is real iff l15%4==0
  // (batch = l15>>2, stored at h row l15>>2); all other lanes read the
  // shared zero row 4 (same-address broadcast within kg groups -> ~free).
  const unsigned arow = ((l15 & 3) == 0)
                      ? (unsigned)((l15 >> 2) * HSTRIDE + kg * 16)
                      : (unsigned)(4 * HSTRIDE + kg * 16);

  // xp A-row mapping: row l15 <-> (batch = l15>>2, time-in-group = l15&3).
  // With C row = 4*kg + r this puts xp(batch=kg, time=t0+r) in reg r of
  // every lane -> gate phase reads acc2[j][tt] with zero data movement.
  const float* pbase = particles +
      ((size_t)(b0 + (l15 >> 2)) * TSEQ + (l15 & 3)) * DPDIM + kg * 8;
  const float* wbase = weights + (size_t)(b0 + kg) * TSEQ;

  // preload group 0 (particles: 4x f32x4; weights: 1x f32x4)
  f32x4 pr[4], wv;
  pr[0] = *(const f32x4*)(pbase);
  pr[1] = *(const f32x4*)(pbase + 4);
  pr[2] = *(const f32x4*)(pbase + 32);
  pr[3] = *(const f32x4*)(pbase + 36);
  wv    = *(const f32x4*)(wbase);

  f32x4 acc[6], acc2[6];
  const f32x4 fzero = {0.f, 0.f, 0.f, 0.f};
  float hreg0 = 0.f, hreg1 = 0.f;

  for (int g = 0; g < 64; ++g) {
    const int t0 = g * 4;

    // ---------------- xp phase: project inputs for t0..t0+3 ----------------
    #pragma unroll
    for (int j = 0; j < 6; ++j) acc2[j] = fzero;
    #pragma unroll
    for (int ks = 0; ks < 2; ++ks) {
      f32x4 pa = pr[ks * 2], pb = pr[ks * 2 + 1];
      ushort8 tmp;
      tmp[0] = f2bf(pa[0]); tmp[1] = f2bf(pa[1]); tmp[2] = f2bf(pa[2]); tmp[3] = f2bf(pa[3]);
      tmp[4] = f2bf(pb[0]); tmp[5] = f2bf(pb[1]); tmp[6] = f2bf(pb[2]); tmp[7] = f2bf(pb[3]);
      bf16x8 af = __builtin_bit_cast(bf16x8, tmp);
      #pragma unroll
      for (int j = 0; j < 6; ++j) {
        const int n = hcol0 + 128 * j;
        bf16x8 bf = *(const bf16x8*)(smem + OFF_WIT + n * 144 + ks * 64 + kg * 16);
        acc2[j] = __builtin_amdgcn_mfma_f32_16x16x32_bf16(af, bf, acc2[j], 0, 0, 0);
      }
    }

    // prefetch next group's inputs (covered by ~4 steps of compute)
    {
      const int t0n = (g < 63) ? (t0 + 4) : 0;   // g=63: dummy re-read of group 0
      const float* pn = pbase + (size_t)t0n * DPDIM;
      pr[0] = *(const f32x4*)(pn);
      pr[1] = *(const f32x4*)(pn + 4);
      pr[2] = *(const f32x4*)(pn + 32);
      pr[3] = *(const f32x4*)(pn + 36);
    }
    f32x4 wvn = *(const f32x4*)(wbase + ((g < 63) ? (t0 + 4) : 0));

    // fold bias + weight-channel: acc2[j][r] += bi[col] + w(batch=kg,t0+r)*Wi64[col]
    #pragma unroll
    for (int j = 0; j < 6; ++j)
      #pragma unroll
      for (int r = 0; r < 4; ++r)
        acc2[j][r] += bi_r[j] + wv[r] * w64_r[j];

    // ---------------- 4 GRU steps ----------------
    #pragma unroll
    for (int tt = 0; tt < 4; ++tt) {
      const int t     = t0 + tt;
      const int rboff = (t & 1) ? OFF_H1 : OFF_H0;   // read buffer
      const int wboff = (t & 1) ? OFF_H0 : OFF_H1;   // write buffer
      #pragma unroll
      for (int j = 0; j < 6; ++j) acc[j] = fzero;
      const char* hb = smem + rboff;
      #pragma unroll
      for (int ks = 0; ks < 8; ++ks) {
        bf16x8 af = *(const bf16x8*)(hb + arow + ks * 64);
        #pragma unroll
        for (int j = 0; j < 6; ++j)
          acc[j] = __builtin_amdgcn_mfma_f32_16x16x32_bf16(af, whb[j][ks], acc[j], 0, 0, 0);
      }
      // Gates: reg 0 of each acc is M-row 4*kg = batch kg; xp comes straight
      // from acc2[j][tt]; previous h is this lane's own hreg.
      float rr0 = sigm(acc2[0][tt] + acc[0][0]);
      float zz0 = sigm(acc2[2][tt] + acc[2][0]);
      float nn0 = tanh_fast(acc2[4][tt] + rr0 * (acc[4][0] + bhn0));
      unsigned short h0u = f2bf(nn0 + zz0 * (hreg0 - nn0));
      hreg0 = bf2f(h0u);
      float rr1 = sigm(acc2[1][tt] + acc[1][0]);
      float zz1 = sigm(acc2[3][tt] + acc[3][0]);
      float nn1 = tanh_fast(acc2[5][tt] + rr1 * (acc[5][0] + bhn1));
      unsigned short h1u = f2bf(nn1 + zz1 * (hreg1 - nn1));
      hreg1 = bf2f(h1u);
      *(unsigned short*)(smem + wboff + kg * HSTRIDE + hcol0 * 2)         = h0u;
      *(unsigned short*)(smem + wboff + kg * HSTRIDE + (hcol0 + 128) * 2) = h1u;
      __syncthreads();
    }
    wv = wvn;
  }

  // epilogue: final h lives in registers -> store directly
  hT[(size_t)(b0 + kg) * 256 + hcol0]       = f2bf(hreg0);
  hT[(size_t)(b0 + kg) * 256 + hcol0 + 128] = f2bf(hreg1);
}

// ---- Head kernel LDS layout ----
#define HOFF_XA 0         // x tile bf16 [64][296] stride 592B
#define HOFF_B  37888     // B stage bf16 [256 n][40 k] stride 80B
#define HOFF_H1 58368     // h1 bf16 [64][264] stride 528B
#define HOFF_H2 92160
#define HOFF_B1 125952
#define HOFF_B2 126976
#define HOFF_W3 128000
#define LDS_HEAD 129024

__global__ __launch_bounds__(256, 2) void head_kernel(
    const unsigned short* __restrict__ hT, const float* __restrict__ action,
    const float* __restrict__ time_idx, const float* __restrict__ W1,
    const float* __restrict__ b1, const float* __restrict__ W2,
    const float* __restrict__ b2, const float* __restrict__ W3,
    const float* __restrict__ b3, float* __restrict__ out)
{
  extern __shared__ char smem[];
  const int tid  = threadIdx.x;
  const int lane = tid & 63;
  const int w    = tid >> 6;
  const int l15  = lane & 15;
  const int kg   = lane >> 4;
  const int c    = blockIdx.x & 1;
  const int rt   = blockIdx.x >> 1;
  const int r0   = rt * 64;

  if (tid < 256) {
    *(float*)(smem + HOFF_B1 + tid * 4) = b1[c * 256 + tid];
    *(float*)(smem + HOFF_B2 + tid * 4) = b2[c * 256 + tid];
    *(float*)(smem + HOFF_W3 + tid * 4) = W3[c * 256 + tid];
  }
  // x = [h | action | t/100 | zero-pad to 288]
  for (int idx = tid; idx < 64 * 296; idx += 256) {
    int row = idx / 296, k = idx - row * 296;
    unsigned short v;
    if (k < 256)       v = hT[(r0 + row) * 256 + k];
    else if (k < 264)  v = f2bf(action[(r0 + row) * 8 + (k - 256)]);
    else if (k == 264) v = f2bf(time_idx[r0 + row] * 0.01f);
    else               v = 0;
    *(unsigned short*)(smem + HOFF_XA + row * 592 + k * 2) = v;
  }

  f32x4 acc[4][4];
  const f32x4 fzero = {0.f, 0.f, 0.f, 0.f};

  // ---- layer 1: h1 = relu(x @ W1[c] + b1[c]), K = 265 padded to 288 ----
  #pragma unroll
  for (int mt = 0; mt < 4; ++mt)
    #pragma unroll
    for (int i = 0; i < 4; ++i) acc[mt][i] = fzero;
  for (int ks = 0; ks < 9; ++ks) {
    for (int idx = tid; idx < 32 * 256; idx += 256) {
      int kk = idx >> 8, n = idx & 255;
      int kglob = ks * 32 + kk;
      float v = (kglob < 265) ? W1[((size_t)c * 265 + kglob) * 256 + n] : 0.f;
      *(unsigned short*)(smem + HOFF_B + n * 80 + kk * 2) = f2bf(v);
    }
    __syncthreads();
    bf16x8 bfr[4];
    #pragma unroll
    for (int i = 0; i < 4; ++i)
      bfr[i] = *(const bf16x8*)(smem + HOFF_B + ((w * 4 + i) * 16 + l15) * 80 + kg * 16);
    #pragma unroll
    for (int mt = 0; mt < 4; ++mt) {
      bf16x8 af = *(const bf16x8*)(smem + HOFF_XA + (mt * 16 + l15) * 592 + ks * 64 + kg * 16);
      #pragma unroll
      for (int i = 0; i < 4; ++i)
        acc[mt][i] = __builtin_amdgcn_mfma_f32_16x16x32_bf16(af, bfr[i], acc[mt][i], 0, 0, 0);
    }
    __syncthreads();
  }
  #pragma unroll
  for (int mt = 0; mt < 4; ++mt)
    #pragma unroll
    for (int i = 0; i < 4; ++i) {
      int col = (w * 4 + i) * 16 + l15;
      float bv = *(const float*)(smem + HOFF_B1 + col * 4);
      #pragma unroll
      for (int r = 0; r < 4; ++r) {
        float v = acc[mt][i][r] + bv; v = v > 0.f ? v : 0.f;
        *(unsigned short*)(smem + HOFF_H1 + (mt * 16 + kg * 4 + r) * 528 + col * 2) = f2bf(v);
      }
    }
  __syncthreads();

  // ---- layer 2: h2 = relu(h1 @ W2[c] + b2[c]), K = 256 ----
  #pragma unroll
  for (int mt = 0; mt < 4; ++mt)
    #pragma unroll
    for (int i = 0; i < 4; ++i) acc[mt][i] = fzero;
  for (int ks = 0; ks < 8; ++ks) {
    for (int idx = tid; idx < 32 * 256; idx += 256) {
      int kk = idx >> 8, n = idx & 255;
      float v = W2[((size_t)c * 256 + ks * 32 + kk) * 256 + n];
      *(unsigned short*)(smem + HOFF_B + n * 80 + kk * 2) = f2bf(v);
    }
    __syncthreads();
    bf16x8 bfr[4];
    #pragma unroll
    for (int i = 0; i < 4; ++i)
      bfr[i] = *(const bf16x8*)(smem + HOFF_B + ((w * 4 + i) * 16 + l15) * 80 + kg * 16);
    #pragma unroll
    for (int mt = 0; mt < 4; ++mt) {
      bf16x8 af = *(const bf16x8*)(smem + HOFF_H1 + (mt * 16 + l15) * 528 + ks * 64 + kg * 16);
      #pragma unroll
      for (int i = 0; i < 4; ++i)
        acc[mt][i] = __builtin_amdgcn_mfma_f32_16x16x32_bf16(af, bfr[i], acc[mt][i], 0, 0, 0);
    }
    __syncthreads();
  }
  #pragma unroll
  for (int mt = 0; mt < 4; ++mt)
    #pragma unroll
    for (int i = 0; i < 4; ++i) {
      int col = (w * 4 + i) * 16 + l15;
      float bv = *(const float*)(smem + HOFF_B2 + col * 4);
      #pragma unroll
      for (int r = 0; r < 4; ++r) {
        float v = acc[mt][i][r] + bv; v = v > 0.f ? v : 0.f;
        *(unsigned short*)(smem + HOFF_H2 + (mt * 16 + kg * 4 + r) * 528 + col * 2) = f2bf(v);
      }
    }
  __syncthreads();

  // ---- layer 3: v = h2 @ W3[c] + b3[c] (VALU dot, 4 threads/row) ----
  {
    int row = tid >> 2, q = tid & 3;
    float s = 0.f;
    #pragma unroll
    for (int i = 0; i < 16; ++i) {
      uint2 hh = *(const uint2*)(smem + HOFF_H2 + row * 528 + (q * 64 + i * 4) * 2);
      const float* w3p = (const float*)(smem + HOFF_W3) + q * 64 + i * 4;
      s += bf2f((unsigned short)hh.x)         * w3p[0];
      s += bf2f((unsigned short)(hh.x >> 16)) * w3p[1];
      s += bf2f((unsigned short)hh.y)         * w3p[2];
      s += bf2f((unsigned short)(hh.y >> 16)) * w3p[3];
    }
    s += __shfl_xor(s, 1);
    s += __shfl_xor(s, 2);
    if (q == 0) out[(r0 + row) * 2 + c] = s + b3[c];
  }
}

extern "C" void kernel_launch(void* const* d_in, const int* in_sizes, int n_in,
                              void* d_out, int out_size, void* d_ws, size_t ws_size,
                              hipStream_t stream) {
  const float* particles = (const float*)d_in[0];
  const float* weights   = (const float*)d_in[1];
  const float* action    = (const float*)d_in[2];
  const float* time_idx  = (const float*)d_in[3];
  const float* Wi        = (const float*)d_in[4];
  const float* bi        = (const float*)d_in[5];
  const float* Wh        = (const float*)d_in[6];
  const float* bhn       = (const float*)d_in[7];
  const float* W1        = (const float*)d_in[8];
  const float* b1        = (const float*)d_in[9];
  const float* W2        = (const float*)d_in[10];
  const float* b2        = (const float*)d_in[11];
  const float* W3        = (const float*)d_in[12];
  const float* b3        = (const float*)d_in[13];
  unsigned short* hT = (unsigned short*)d_ws;   // [1024][256] bf16
  float* out = (float*)d_out;

  (void)hipFuncSetAttribute((const void*)gru_kernel,
                            hipFuncAttributeMaxDynamicSharedMemorySize, LDS_GRU);
  (void)hipFuncSetAttribute((const void*)head_kernel,
                            hipFuncAttributeMaxDynamicSharedMemorySize, LDS_HEAD);

  hipLaunchKernelGGL(gru_kernel, dim3(256), dim3(512), LDS_GRU, stream,
                     particles, weights, Wi, bi, Wh, bhn, hT);
  hipLaunchKernelGGL(head_kernel, dim3(32), dim3(256), LDS_HEAD, stream,
                     hT, action, time_idx, W1, b1, W2, b2, W3, b3, out);
}

// Round 3
// 752.048 us; speedup vs baseline: 2.2553x; 2.2553x over previous
//
#include <hip/hip_runtime.h>

// ---------------------------------------------------------------------------
// CriticNetwork: GRU over T=256 steps (B=1024, H=256, F=65) + 2-critic MLP.
// Kernel 1 (gru_kernel): persistent, 256 blocks x 512 thr (8 waves, 2/SIMD).
//   Wh held as bf16 MFMA B-fragments in REGISTERS (192 V+A; hard cap is 256
//   per wave since 8 waves/block must co-reside 2/SIMD -> every other buffer
//   must be transient or LDS. Round-2 lesson: +60 persistent regs => spill
//   => 1.6 GB scratch writes, 2.5x slower).
//   xp M-row mapping: row i <-> (batch=i>>2, time=i&3) so the xp C-fragment
//   writer lane == gate-phase reader lane. xp goes through a lane-aligned
//   LDS slot [col][batch(kg)][time] bf16: one b64 write per j per group,
//   one u16 lane-local read per j per step (no strided 8-way conflicts, no
//   uint2 unpack). h kept in a register (no ho re-read); LDS h write remains
//   for other waves' A-fragments. bi/w64 read from LDS transiently.
// Kernel 2 (head_kernel): twin critic MLPs, 32 blocks, MFMA. (unchanged)
// ---------------------------------------------------------------------------

#define TSEQ 256
#define DPDIM 64

typedef float f32x4 __attribute__((ext_vector_type(4)));
typedef __bf16 bf16x8 __attribute__((ext_vector_type(8)));
typedef unsigned short ushort8 __attribute__((ext_vector_type(8)));

static __device__ __forceinline__ unsigned short f2bf(float f) {
  unsigned u = __builtin_bit_cast(unsigned, f);
  return (unsigned short)((u + 0x7fffu + ((u >> 16) & 1u)) >> 16);  // RNE
}
static __device__ __forceinline__ float bf2f(unsigned short h) {
  return __builtin_bit_cast(float, ((unsigned)h) << 16);
}
static __device__ __forceinline__ float sigm(float x) {
  return __builtin_amdgcn_rcpf(1.f + __expf(-x));
}
static __device__ __forceinline__ float tanh_fast(float p) {
  float q = __expf(-2.f * fabsf(p));
  float t = (1.f - q) * __builtin_amdgcn_rcpf(1.f + q);
  return __builtin_bit_cast(float, __builtin_bit_cast(unsigned, t) |
                                   (__builtin_bit_cast(unsigned, p) & 0x80000000u));
}

// ---- GRU kernel LDS layout (bytes) ----
#define OFF_WIT 0         // Wi transposed bf16 [768 n][72 k-stride] = 768*144
#define OFF_XP  110592    // xp bf16 [768 col][4 batch][4 time] = 768*32
#define OFF_H0  135168    // h buf0 bf16 [4 real rows + 1 zero row][272] stride 544B
#define OFF_H1  137888    // h buf1 (same shape)
#define OFF_BI  140608    // bi f32 [768]
#define OFF_W64 143680    // Wi row 64 (weight channel) f32 [768]
#define LDS_GRU 146752

#define HSTRIDE 544       // h row stride in bytes (2-way max bank pattern)

__global__ __launch_bounds__(512, 2) void gru_kernel(
    const float* __restrict__ particles, const float* __restrict__ weights,
    const float* __restrict__ Wi, const float* __restrict__ bi,
    const float* __restrict__ Wh, const float* __restrict__ bhn,
    unsigned short* __restrict__ hT)
{
  extern __shared__ char smem[];
  const int tid  = threadIdx.x;
  const int lane = tid & 63;
  const int w    = tid >> 6;      // wave id 0..7
  const int l15  = lane & 15;
  const int kg   = lane >> 4;     // k-group 0..3
  const int b0   = blockIdx.x * 4;

  // ---------------- prologue ----------------
  // Wi rows 0..63 -> LDS transposed bf16 (B-operand friendly: k contiguous per n)
  for (int idx = tid; idx < 64 * 768; idx += 512) {
    int k = idx / 768, n = idx - k * 768;
    *(unsigned short*)(smem + OFF_WIT + n * 144 + k * 2) = f2bf(Wi[idx]);
  }
  for (int idx = tid; idx < 768; idx += 512) {
    *(float*)(smem + OFF_BI  + idx * 4) = bi[idx];
    *(float*)(smem + OFF_W64 + idx * 4) = Wi[64 * 768 + idx];
  }
  // zero both h buffers (incl. the shared zero row 4, never written again)
  for (int idx = tid; idx < (2 * 5 * HSTRIDE) / 4; idx += 512)
    ((unsigned*)(smem + OFF_H0))[idx] = 0u;

  const int hcol0 = w * 16 + l15;       // p=0 col; p=1 col = hcol0+128
  const float bhn0 = bhn[hcol0];
  const float bhn1 = bhn[hcol0 + 128];

  // Wh -> register B-fragments. Wave w owns N-tiles {w+8j}, j=0..5:
  //   j=0,1 -> r-gate tiles (hidden tiles w, w+8); j=2,3 -> z; j=4,5 -> n.
  bf16x8 whb[6][8];
  #pragma unroll
  for (int j = 0; j < 6; ++j) {
    const int tile = w + 8 * j;
    const float* wp = Wh + (size_t)(kg * 8) * 768 + tile * 16 + l15;
    #pragma unroll
    for (int ks = 0; ks < 8; ++ks) {
      ushort8 tmp;
      #pragma unroll
      for (int e = 0; e < 8; ++e)
        tmp[e] = f2bf(wp[(size_t)(ks * 32 + e) * 768]);
      whb[j][ks] = __builtin_bit_cast(bf16x8, tmp);
    }
  }
  __syncthreads();

  // A-fragment source for the recurrence: M-row l15 is real iff l15%4==0
  // (batch = l15>>2, stored at h row l15>>2); all other lanes read the
  // shared zero row 4 (same-address broadcast -> ~free; <=3 distinct
  // addresses per bank-quad).
  const unsigned arow = ((l15 & 3) == 0)
                      ? (unsigned)((l15 >> 2) * HSTRIDE + kg * 16)
                      : (unsigned)(4 * HSTRIDE + kg * 16);

  // xp A-row mapping: row l15 <-> (batch = l15>>2, time-in-group = l15&3).
  // C row = 4*kg + r  =>  lane (l15,kg) reg r = xp(batch=kg, time=t0+r),
  // i.e. writer lane == gate reader lane for the XP slot below.
  const float* pbase = particles +
      ((size_t)(b0 + (l15 >> 2)) * TSEQ + (l15 & 3)) * DPDIM + kg * 8;
  const float* wbase = weights + (size_t)(b0 + kg) * TSEQ;

  // lane-private XP slot base: col*32 + kg*8 (+ j*4096 + tt*2)
  char* const xpb = smem + OFF_XP + hcol0 * 32 + kg * 8;

  f32x4 acc[6];
  const f32x4 fzero = {0.f, 0.f, 0.f, 0.f};
  float hreg0 = 0.f, hreg1 = 0.f;

  for (int g = 0; g < 64; ++g) {
    const int t0 = g * 4;

    // ---------------- xp phase: project inputs for t0..t0+3 ----------------
    #pragma unroll
    for (int j = 0; j < 6; ++j) acc[j] = fzero;
    #pragma unroll
    for (int ks = 0; ks < 2; ++ks) {
      const float* pp = pbase + (size_t)t0 * DPDIM + ks * 32;
      f32x4 pa = *(const f32x4*)pp;
      f32x4 pb = *(const f32x4*)(pp + 4);
      ushort8 tmp;
      tmp[0] = f2bf(pa[0]); tmp[1] = f2bf(pa[1]); tmp[2] = f2bf(pa[2]); tmp[3] = f2bf(pa[3]);
      tmp[4] = f2bf(pb[0]); tmp[5] = f2bf(pb[1]); tmp[6] = f2bf(pb[2]); tmp[7] = f2bf(pb[3]);
      bf16x8 af = __builtin_bit_cast(bf16x8, tmp);
      #pragma unroll
      for (int j = 0; j < 6; ++j) {
        const int n = hcol0 + 128 * j;
        bf16x8 bf = *(const bf16x8*)(smem + OFF_WIT + n * 144 + ks * 64 + kg * 16);
        acc[j] = __builtin_amdgcn_mfma_f32_16x16x32_bf16(af, bf, acc[j], 0, 0, 0);
      }
    }
    // fold bias + weight-channel (transient LDS reads, f32 precision as r1),
    // pack to bf16 and park in the lane-private XP slot.
    {
      f32x4 wv = *(const f32x4*)(wbase + t0);
      #pragma unroll
      for (int j = 0; j < 6; ++j) {
        const int col = hcol0 + 128 * j;
        const float biv  = *(const float*)(smem + OFF_BI  + col * 4);
        const float w64v = *(const float*)(smem + OFF_W64 + col * 4);
        float v0 = acc[j][0] + biv + wv[0] * w64v;
        float v1 = acc[j][1] + biv + wv[1] * w64v;
        float v2 = acc[j][2] + biv + wv[2] * w64v;
        float v3 = acc[j][3] + biv + wv[3] * w64v;
        uint2 val;
        val.x = (unsigned)f2bf(v0) | ((unsigned)f2bf(v1) << 16);
        val.y = (unsigned)f2bf(v2) | ((unsigned)f2bf(v3) << 16);
        *(uint2*)(xpb + j * 4096) = val;   // writer == only reader (same lane)
      }
    }

    // ---------------- 4 GRU steps ----------------
    #pragma unroll
    for (int tt = 0; tt < 4; ++tt) {
      const int t     = t0 + tt;
      const int rboff = (t & 1) ? OFF_H1 : OFF_H0;   // read buffer
      const int wboff = (t & 1) ? OFF_H0 : OFF_H1;   // write buffer
      #pragma unroll
      for (int j = 0; j < 6; ++j) acc[j] = fzero;
      const char* hb = smem + rboff;
      #pragma unroll
      for (int ks = 0; ks < 8; ++ks) {
        bf16x8 af = *(const bf16x8*)(hb + arow + ks * 64);
        #pragma unroll
        for (int j = 0; j < 6; ++j)
          acc[j] = __builtin_amdgcn_mfma_f32_16x16x32_bf16(af, whb[j][ks], acc[j], 0, 0, 0);
      }
      // Gates: reg 0 of each acc is M-row 4*kg = batch kg; xp comes from the
      // lane-private XP slot (u16, lane-aligned); previous h is hreg.
      float xr0 = bf2f(*(const unsigned short*)(xpb + 0 * 4096 + tt * 2));
      float xr1 = bf2f(*(const unsigned short*)(xpb + 1 * 4096 + tt * 2));
      float xz0 = bf2f(*(const unsigned short*)(xpb + 2 * 4096 + tt * 2));
      float xz1 = bf2f(*(const unsigned short*)(xpb + 3 * 4096 + tt * 2));
      float xn0 = bf2f(*(const unsigned short*)(xpb + 4 * 4096 + tt * 2));
      float xn1 = bf2f(*(const unsigned short*)(xpb + 5 * 4096 + tt * 2));
      float rr0 = sigm(xr0 + acc[0][0]);
      float zz0 = sigm(xz0 + acc[2][0]);
      float nn0 = tanh_fast(xn0 + rr0 * (acc[4][0] + bhn0));
      unsigned short h0u = f2bf(nn0 + zz0 * (hreg0 - nn0));
      hreg0 = bf2f(h0u);
      float rr1 = sigm(xr1 + acc[1][0]);
      float zz1 = sigm(xz1 + acc[3][0]);
      float nn1 = tanh_fast(xn1 + rr1 * (acc[5][0] + bhn1));
      unsigned short h1u = f2bf(nn1 + zz1 * (hreg1 - nn1));
      hreg1 = bf2f(h1u);
      *(unsigned short*)(smem + wboff + kg * HSTRIDE + hcol0 * 2)         = h0u;
      *(unsigned short*)(smem + wboff + kg * HSTRIDE + (hcol0 + 128) * 2) = h1u;
      __syncthreads();
    }
  }

  // epilogue: final h lives in registers -> store directly
  hT[(size_t)(b0 + kg) * 256 + hcol0]       = f2bf(hreg0);
  hT[(size_t)(b0 + kg) * 256 + hcol0 + 128] = f2bf(hreg1);
}

// ---- Head kernel LDS layout ----
#define HOFF_XA 0         // x tile bf16 [64][296] stride 592B
#define HOFF_B  37888     // B stage bf16 [256 n][40 k] stride 80B
#define HOFF_H1 58368     // h1 bf16 [64][264] stride 528B
#define HOFF_H2 92160
#define HOFF_B1 125952
#define HOFF_B2 126976
#define HOFF_W3 128000
#define LDS_HEAD 129024

__global__ __launch_bounds__(256, 2) void head_kernel(
    const unsigned short* __restrict__ hT, const float* __restrict__ action,
    const float* __restrict__ time_idx, const float* __restrict__ W1,
    const float* __restrict__ b1, const float* __restrict__ W2,
    const float* __restrict__ b2, const float* __restrict__ W3,
    const float* __restrict__ b3, float* __restrict__ out)
{
  extern __shared__ char smem[];
  const int tid  = threadIdx.x;
  const int lane = tid & 63;
  const int w    = tid >> 6;
  const int l15  = lane & 15;
  const int kg   = lane >> 4;
  const int c    = blockIdx.x & 1;
  const int rt   = blockIdx.x >> 1;
  const int r0   = rt * 64;

  if (tid < 256) {
    *(float*)(smem + HOFF_B1 + tid * 4) = b1[c * 256 + tid];
    *(float*)(smem + HOFF_B2 + tid * 4) = b2[c * 256 + tid];
    *(float*)(smem + HOFF_W3 + tid * 4) = W3[c * 256 + tid];
  }
  // x = [h | action | t/100 | zero-pad to 288]
  for (int idx = tid; idx < 64 * 296; idx += 256) {
    int row = idx / 296, k = idx - row * 296;
    unsigned short v;
    if (k < 256)       v = hT[(r0 + row) * 256 + k];
    else if (k < 264)  v = f2bf(action[(r0 + row) * 8 + (k - 256)]);
    else if (k == 264) v = f2bf(time_idx[r0 + row] * 0.01f);
    else               v = 0;
    *(unsigned short*)(smem + HOFF_XA + row * 592 + k * 2) = v;
  }

  f32x4 acc[4][4];
  const f32x4 fzero = {0.f, 0.f, 0.f, 0.f};

  // ---- layer 1: h1 = relu(x @ W1[c] + b1[c]), K = 265 padded to 288 ----
  #pragma unroll
  for (int mt = 0; mt < 4; ++mt)
    #pragma unroll
    for (int i = 0; i < 4; ++i) acc[mt][i] = fzero;
  for (int ks = 0; ks < 9; ++ks) {
    for (int idx = tid; idx < 32 * 256; idx += 256) {
      int kk = idx >> 8, n = idx & 255;
      int kglob = ks * 32 + kk;
      float v = (kglob < 265) ? W1[((size_t)c * 265 + kglob) * 256 + n] : 0.f;
      *(unsigned short*)(smem + HOFF_B + n * 80 + kk * 2) = f2bf(v);
    }
    __syncthreads();
    bf16x8 bfr[4];
    #pragma unroll
    for (int i = 0; i < 4; ++i)
      bfr[i] = *(const bf16x8*)(smem + HOFF_B + ((w * 4 + i) * 16 + l15) * 80 + kg * 16);
    #pragma unroll
    for (int mt = 0; mt < 4; ++mt) {
      bf16x8 af = *(const bf16x8*)(smem + HOFF_XA + (mt * 16 + l15) * 592 + ks * 64 + kg * 16);
      #pragma unroll
      for (int i = 0; i < 4; ++i)
        acc[mt][i] = __builtin_amdgcn_mfma_f32_16x16x32_bf16(af, bfr[i], acc[mt][i], 0, 0, 0);
    }
    __syncthreads();
  }
  #pragma unroll
  for (int mt = 0; mt < 4; ++mt)
    #pragma unroll
    for (int i = 0; i < 4; ++i) {
      int col = (w * 4 + i) * 16 + l15;
      float bv = *(const float*)(smem + HOFF_B1 + col * 4);
      #pragma unroll
      for (int r = 0; r < 4; ++r) {
        float v = acc[mt][i][r] + bv; v = v > 0.f ? v : 0.f;
        *(unsigned short*)(smem + HOFF_H1 + (mt * 16 + kg * 4 + r) * 528 + col * 2) = f2bf(v);
      }
    }
  __syncthreads();

  // ---- layer 2: h2 = relu(h1 @ W2[c] + b2[c]), K = 256 ----
  #pragma unroll
  for (int mt = 0; mt < 4; ++mt)
    #pragma unroll
    for (int i = 0; i < 4; ++i) acc[mt][i] = fzero;
  for (int ks = 0; ks < 8; ++ks) {
    for (int idx = tid; idx < 32 * 256; idx += 256) {
      int kk = idx >> 8, n = idx & 255;
      float v = W2[((size_t)c * 256 + ks * 32 + kk) * 256 + n];
      *(unsigned short*)(smem + HOFF_B + n * 80 + kk * 2) = f2bf(v);
    }
    __syncthreads();
    bf16x8 bfr[4];
    #pragma unroll
    for (int i = 0; i < 4; ++i)
      bfr[i] = *(const bf16x8*)(smem + HOFF_B + ((w * 4 + i) * 16 + l15) * 80 + kg * 16);
    #pragma unroll
    for (int mt = 0; mt < 4; ++mt) {
      bf16x8 af = *(const bf16x8*)(smem + HOFF_H1 + (mt * 16 + l15) * 528 + ks * 64 + kg * 16);
      #pragma unroll
      for (int i = 0; i < 4; ++i)
        acc[mt][i] = __builtin_amdgcn_mfma_f32_16x16x32_bf16(af, bfr[i], acc[mt][i], 0, 0, 0);
    }
    __syncthreads();
  }
  #pragma unroll
  for (int mt = 0; mt < 4; ++mt)
    #pragma unroll
    for (int i = 0; i < 4; ++i) {
      int col = (w * 4 + i) * 16 + l15;
      float bv = *(const float*)(smem + HOFF_B2 + col * 4);
      #pragma unroll
      for (int r = 0; r < 4; ++r) {
        float v = acc[mt][i][r] + bv; v = v > 0.f ? v : 0.f;
        *(unsigned short*)(smem + HOFF_H2 + (mt * 16 + kg * 4 + r) * 528 + col * 2) = f2bf(v);
      }
    }
  __syncthreads();

  // ---- layer 3: v = h2 @ W3[c] + b3[c] (VALU dot, 4 threads/row) ----
  {
    int row = tid >> 2, q = tid & 3;
    float s = 0.f;
    #pragma unroll
    for (int i = 0; i < 16; ++i) {
      uint2 hh = *(const uint2*)(smem + HOFF_H2 + row * 528 + (q * 64 + i * 4) * 2);
      const float* w3p = (const float*)(smem + HOFF_W3) + q * 64 + i * 4;
      s += bf2f((unsigned short)hh.x)         * w3p[0];
      s += bf2f((unsigned short)(hh.x >> 16)) * w3p[1];
      s += bf2f((unsigned short)hh.y)         * w3p[2];
      s += bf2f((unsigned short)(hh.y >> 16)) * w3p[3];
    }
    s += __shfl_xor(s, 1);
    s += __shfl_xor(s, 2);
    if (q == 0) out[(r0 + row) * 2 + c] = s + b3[c];
  }
}

extern "C" void kernel_launch(void* const* d_in, const int* in_sizes, int n_in,
                              void* d_out, int out_size, void* d_ws, size_t ws_size,
                              hipStream_t stream) {
  const float* particles = (const float*)d_in[0];
  const float* weights   = (const float*)d_in[1];
  const float* action    = (const float*)d_in[2];
  const float* time_idx  = (const float*)d_in[3];
  const float* Wi        = (const float*)d_in[4];
  const float* bi        = (const float*)d_in[5];
  const float* Wh        = (const float*)d_in[6];
  const float* bhn       = (const float*)d_in[7];
  const float* W1        = (const float*)d_in[8];
  const float* b1        = (const float*)d_in[9];
  const float* W2        = (const float*)d_in[10];
  const float* b2        = (const float*)d_in[11];
  const float* W3        = (const float*)d_in[12];
  const float* b3        = (const float*)d_in[13];
  unsigned short* hT = (unsigned short*)d_ws;   // [1024][256] bf16
  float* out = (float*)d_out;

  (void)hipFuncSetAttribute((const void*)gru_kernel,
                            hipFuncAttributeMaxDynamicSharedMemorySize, LDS_GRU);
  (void)hipFuncSetAttribute((const void*)head_kernel,
                            hipFuncAttributeMaxDynamicSharedMemorySize, LDS_HEAD);

  hipLaunchKernelGGL(gru_kernel, dim3(256), dim3(512), LDS_GRU, stream,
                     particles, weights, Wi, bi, Wh, bhn, hT);
  hipLaunchKernelGGL(head_kernel, dim3(32), dim3(256), LDS_HEAD, stream,
                     hT, action, time_idx, W1, b1, W2, b2, W3, b3, out);
}